// Round 5
// baseline (456.628 us; speedup 1.0000x reference)
//
#include <hip/hip_runtime.h>

#define ALPHA 0.2f

typedef __attribute__((ext_vector_type(8))) short bf16x8;
typedef __attribute__((ext_vector_type(4))) float f32x4;

static __device__ __forceinline__ float leaky_f(float v) {
  return v >= 0.0f ? v : ALPHA * v;
}

static __device__ __forceinline__ unsigned short f2bf(float f) {
  unsigned u = __float_as_uint(f);
  unsigned r = (u + 0x7FFFu + ((u >> 16) & 1u)) >> 16;
  return (unsigned short)r;
}
static __device__ __forceinline__ float bf2f(unsigned short h) {
  return __uint_as_float(((unsigned)h) << 16);
}

typedef const __attribute__((address_space(1))) unsigned char* gas1_t;
typedef __attribute__((address_space(3))) unsigned char* las3_t;
static __device__ __forceinline__ void gll16(const void* g, void* l) {
  __builtin_amdgcn_global_load_lds((gas1_t)g, (las3_t)l, 16, 0, 0);
}

// ---------- CSR build ----------

__global__ __launch_bounds__(256) void zero_int_kernel(int* __restrict__ p, int n) {
  int i = blockIdx.x * blockDim.x + threadIdx.x;
  if (i < n) p[i] = 0;
}

__global__ __launch_bounds__(256) void hist_kernel(const int* __restrict__ dst,
                                                   int* __restrict__ cnt, int E) {
  int e = blockIdx.x * blockDim.x + threadIdx.x;
  if (e < E) atomicAdd(&cnt[dst[e]], 1);
}

__global__ __launch_bounds__(256) void blocksum_kernel(const int* __restrict__ deg,
                                                       int* __restrict__ blksum, int n) {
  __shared__ int red[4];
  int i = blockIdx.x * 256 + threadIdx.x;
  int v = (i < n) ? deg[i] : 0;
  #pragma unroll
  for (int off = 32; off; off >>= 1) v += __shfl_down(v, off, 64);
  int wv = threadIdx.x >> 6, ln = threadIdx.x & 63;
  if (ln == 0) red[wv] = v;
  __syncthreads();
  if (threadIdx.x == 0) blksum[blockIdx.x] = red[0] + red[1] + red[2] + red[3];
}

__global__ __launch_bounds__(1024) void scanblk_kernel(int* __restrict__ blksum,
                                                       int* __restrict__ off, int nb, int n) {
  __shared__ int s[1024];
  int t = threadIdx.x;
  int v = (t < nb) ? blksum[t] : 0;
  s[t] = v;
  __syncthreads();
  for (int d = 1; d < 1024; d <<= 1) {
    int u = (t >= d) ? s[t - d] : 0;
    __syncthreads();
    s[t] += u;
    __syncthreads();
  }
  if (t < nb) blksum[t] = s[t] - v;
  if (t == 0) off[n] = s[1023];
}

__global__ __launch_bounds__(256) void scatteroff_kernel(const int* __restrict__ blkoff,
                                                         int* __restrict__ off,
                                                         int* __restrict__ cursor, int n) {
  __shared__ int s[256];
  int i = blockIdx.x * 256 + threadIdx.x;
  int v = (i < n) ? cursor[i] : 0;
  s[threadIdx.x] = v;
  __syncthreads();
  for (int d = 1; d < 256; d <<= 1) {
    int u = (threadIdx.x >= d) ? s[threadIdx.x - d] : 0;
    __syncthreads();
    s[threadIdx.x] += u;
    __syncthreads();
  }
  int excl = s[threadIdx.x] - v + blkoff[blockIdx.x];
  if (i < n) {
    off[i] = excl;
    cursor[i] = excl;
  }
}

__global__ __launch_bounds__(256) void fill_kernel(const int* __restrict__ src,
                                                   const int* __restrict__ dst,
                                                   int* __restrict__ cursor,
                                                   int* __restrict__ csr, int E) {
  int e = blockIdx.x * blockDim.x + threadIdx.x;
  if (e < E) {
    int p = atomicAdd(&cursor[dst[e]], 1);
    csr[p] = src[e];
  }
}

// ---------- aggregation: agg[i] = x[i] + sum_p x[csr[p]]; emits bf16 hi/lo ----------
template <int F4>
__global__ __launch_bounds__(256) void gather_agg_split(const float* __restrict__ x,
                                                        const int* __restrict__ off,
                                                        const int* __restrict__ csr,
                                                        unsigned short* __restrict__ Ah,
                                                        unsigned short* __restrict__ Al,
                                                        int M) {
  constexpr int GP = 256 / F4;
  int g = threadIdx.x / F4;
  int lane = threadIdx.x % F4;
  int node = blockIdx.x * GP + g;
  if (node >= M) return;
  const float4* xv = reinterpret_cast<const float4*>(x);
  float4 a0 = xv[(size_t)node * F4 + lane];
  float4 a1 = make_float4(0.f, 0.f, 0.f, 0.f);
  float4 a2 = make_float4(0.f, 0.f, 0.f, 0.f);
  float4 a3 = make_float4(0.f, 0.f, 0.f, 0.f);
  int p = off[node], p1 = off[node + 1];
  for (; p + 4 <= p1; p += 4) {
    int s0 = csr[p], s1 = csr[p + 1], s2 = csr[p + 2], s3 = csr[p + 3];
    float4 v0 = xv[(size_t)s0 * F4 + lane];
    float4 v1 = xv[(size_t)s1 * F4 + lane];
    float4 v2 = xv[(size_t)s2 * F4 + lane];
    float4 v3 = xv[(size_t)s3 * F4 + lane];
    a0.x += v0.x; a0.y += v0.y; a0.z += v0.z; a0.w += v0.w;
    a1.x += v1.x; a1.y += v1.y; a1.z += v1.z; a1.w += v1.w;
    a2.x += v2.x; a2.y += v2.y; a2.z += v2.z; a2.w += v2.w;
    a3.x += v3.x; a3.y += v3.y; a3.z += v3.z; a3.w += v3.w;
  }
  for (; p < p1; ++p) {
    int s = csr[p];
    float4 v = xv[(size_t)s * F4 + lane];
    a0.x += v.x; a0.y += v.y; a0.z += v.z; a0.w += v.w;
  }
  float4 acc;
  acc.x = (a0.x + a1.x) + (a2.x + a3.x);
  acc.y = (a0.y + a1.y) + (a2.y + a3.y);
  acc.z = (a0.z + a1.z) + (a2.z + a3.z);
  acc.w = (a0.w + a1.w) + (a2.w + a3.w);
  unsigned short h0 = f2bf(acc.x), h1 = f2bf(acc.y), h2 = f2bf(acc.z), h3 = f2bf(acc.w);
  uint2 hv, lv;
  hv.x = (unsigned)h0 | ((unsigned)h1 << 16);
  hv.y = (unsigned)h2 | ((unsigned)h3 << 16);
  lv.x = (unsigned)f2bf(acc.x - bf2f(h0)) | ((unsigned)f2bf(acc.y - bf2f(h1)) << 16);
  lv.y = (unsigned)f2bf(acc.z - bf2f(h2)) | ((unsigned)f2bf(acc.w - bf2f(h3)) << 16);
  size_t base = (size_t)node * (F4 * 4) + (size_t)lane * 4;
  *reinterpret_cast<uint2*>(&Ah[base]) = hv;
  *reinterpret_cast<uint2*>(&Al[base]) = lv;
}

// ---------- weight prep: W [K][N] f32 -> Wh, Wl [N][K] bf16 ----------
__global__ __launch_bounds__(256) void prep_w(const float* __restrict__ W,
                                              unsigned short* __restrict__ Wh,
                                              unsigned short* __restrict__ Wl,
                                              int K, int N) {
  __shared__ float T[32][65];
  int k0 = blockIdx.x * 32, n0 = blockIdx.y * 64;
  int t = threadIdx.x;
  int nn = t & 63, kk0 = t >> 6;
  #pragma unroll
  for (int i = 0; i < 8; ++i) {
    int kk = kk0 + i * 4;
    T[kk][nn] = W[(size_t)(k0 + kk) * N + n0 + nn];
  }
  __syncthreads();
  int kk = t & 31, nb = t >> 5;
  #pragma unroll
  for (int i = 0; i < 8; ++i) {
    int n2 = nb + i * 8;
    float f = T[kk][n2];
    unsigned short h = f2bf(f);
    float r = f - bf2f(h);
    Wh[(size_t)(n0 + n2) * K + k0 + kk] = h;
    Wl[(size_t)(n0 + n2) * K + k0 + kk] = f2bf(r);
  }
}

// ---------- GEMM: C = leaky(A@W + bias), A pre-split bf16 hi/lo [M][K], W [N][K] hi/lo.
// OUT_MODE 0: write bf16 hi/lo pair; 1: write f32; 2: fused out[row]=sum leaky*w5 + b5 (N==128)
template <int OUT_MODE>
__global__ __launch_bounds__(256, 3) void gemm_bf16(const unsigned short* __restrict__ Ah,
                                                    const unsigned short* __restrict__ Al,
                                                    const unsigned short* __restrict__ Bh,
                                                    const unsigned short* __restrict__ Bl,
                                                    const float* __restrict__ bias,
                                                    unsigned short* __restrict__ Ch,
                                                    unsigned short* __restrict__ Cl,
                                                    float* __restrict__ Cf,
                                                    int M, int N, int K,
                                                    const float* __restrict__ w5,
                                                    const float* __restrict__ b5p,
                                                    float* __restrict__ out) {
  __shared__ unsigned short Ah_s[128 * 32];
  __shared__ unsigned short Al_s[128 * 32];
  __shared__ unsigned short Bh_s[128 * 32];
  __shared__ unsigned short Bl_s[128 * 32];
  __shared__ float part_s[128][2];

  const int tid = threadIdx.x;
  const int bm = blockIdx.x * 128, bn = blockIdx.y * 128;
  const int lane = tid & 63;
  const int wave = tid >> 6;
  const int wr = (wave >> 1) * 64;
  const int wc = (wave & 1) * 64;
  const int lrow = lane & 15;
  const int lslot = lane >> 4;

  f32x4 acc[4][4];
  #pragma unroll
  for (int mi = 0; mi < 4; ++mi)
    #pragma unroll
    for (int ni = 0; ni < 4; ++ni)
      acc[mi][ni] = (f32x4){0.f, 0.f, 0.f, 0.f};

  for (int k0 = 0; k0 < K; k0 += 32) {
    // stage 4 tiles (128x32 bf16 each, linear) via global_load_lds 16B
    #pragma unroll
    for (int h = 0; h < 2; ++h) {
      int p = tid + h * 256;          // 512 segs of 16B per tile
      int row = p >> 2, seg = p & 3;
      size_t ga = (size_t)(bm + row) * K + k0 + seg * 8;
      size_t gb = (size_t)(bn + row) * K + k0 + seg * 8;
      int lo = p * 8;                 // bf16 elems
      gll16(Ah + ga, Ah_s + lo);
      gll16(Al + ga, Al_s + lo);
      gll16(Bh + gb, Bh_s + lo);
      gll16(Bl + gb, Bl_s + lo);
    }
    __syncthreads();

    bf16x8 fah[4], fal[4], fbh[4], fbl[4];
    #pragma unroll
    for (int mi = 0; mi < 4; ++mi) {
      int off = (wr + mi * 16 + lrow) * 32 + lslot * 8;
      fah[mi] = *reinterpret_cast<const bf16x8*>(&Ah_s[off]);
      fal[mi] = *reinterpret_cast<const bf16x8*>(&Al_s[off]);
    }
    #pragma unroll
    for (int ni = 0; ni < 4; ++ni) {
      int off = (wc + ni * 16 + lrow) * 32 + lslot * 8;
      fbh[ni] = *reinterpret_cast<const bf16x8*>(&Bh_s[off]);
      fbl[ni] = *reinterpret_cast<const bf16x8*>(&Bl_s[off]);
    }
    #pragma unroll
    for (int mi = 0; mi < 4; ++mi)
      #pragma unroll
      for (int ni = 0; ni < 4; ++ni) {
        acc[mi][ni] = __builtin_amdgcn_mfma_f32_16x16x32_bf16(fah[mi], fbh[ni], acc[mi][ni], 0, 0, 0);
        acc[mi][ni] = __builtin_amdgcn_mfma_f32_16x16x32_bf16(fah[mi], fbl[ni], acc[mi][ni], 0, 0, 0);
        acc[mi][ni] = __builtin_amdgcn_mfma_f32_16x16x32_bf16(fal[mi], fbh[ni], acc[mi][ni], 0, 0, 0);
      }
    __syncthreads();
  }

  if (OUT_MODE == 2) {
    float w5v[4], bv[4];
    #pragma unroll
    for (int ni = 0; ni < 4; ++ni) {
      int col = wc + ni * 16 + lrow;
      w5v[ni] = w5[col];
      bv[ni] = bias[col];
    }
    #pragma unroll
    for (int mi = 0; mi < 4; ++mi) {
      #pragma unroll
      for (int j = 0; j < 4; ++j) {
        float s = 0.f;
        #pragma unroll
        for (int ni = 0; ni < 4; ++ni)
          s += leaky_f(acc[mi][ni][j] + bv[ni]) * w5v[ni];
        s += __shfl_xor(s, 1, 64);
        s += __shfl_xor(s, 2, 64);
        s += __shfl_xor(s, 4, 64);
        s += __shfl_xor(s, 8, 64);
        if (lrow == 0) part_s[wr + mi * 16 + lslot * 4 + j][wave & 1] = s;
      }
    }
    __syncthreads();
    if (tid < 128) {
      int row = bm + tid;
      if (row < M) out[row] = part_s[tid][0] + part_s[tid][1] + b5p[0];
    }
  } else {
    #pragma unroll
    for (int ni = 0; ni < 4; ++ni) {
      int col = bn + wc + ni * 16 + lrow;
      float bv = bias[col];
      #pragma unroll
      for (int mi = 0; mi < 4; ++mi) {
        int rbase = bm + wr + mi * 16 + lslot * 4;
        #pragma unroll
        for (int j = 0; j < 4; ++j) {
          int row = rbase + j;
          if (row < M) {
            float v = leaky_f(acc[mi][ni][j] + bv);
            if (OUT_MODE == 0) {
              unsigned short h = f2bf(v);
              Ch[(size_t)row * N + col] = h;
              Cl[(size_t)row * N + col] = f2bf(v - bf2f(h));
            } else {
              Cf[(size_t)row * N + col] = v;
            }
          }
        }
      }
    }
  }
}

extern "C" void kernel_launch(void* const* d_in, const int* in_sizes, int n_in,
                              void* d_out, int out_size, void* d_ws, size_t ws_size,
                              hipStream_t stream) {
  const float* x  = (const float*)d_in[0];
  const int*   ei = (const int*)d_in[2];
  const float* W1 = (const float*)d_in[3];
  const float* b1 = (const float*)d_in[4];
  const float* W2 = (const float*)d_in[5];
  const float* b2 = (const float*)d_in[6];
  const float* W3 = (const float*)d_in[7];
  const float* b3 = (const float*)d_in[8];
  const float* W4 = (const float*)d_in[9];
  const float* b4 = (const float*)d_in[10];
  const float* W5 = (const float*)d_in[11];
  const float* b5 = (const float*)d_in[12];
  float* out = (float*)d_out;

  const int M = in_sizes[0] / 128;  // 50000
  const int E = in_sizes[2] / 2;    // 800000
  const int* src = ei;
  const int* dst = ei + E;
  const int MR = ((M + 127) / 128) * 128;  // 50048

  // ---- workspace layout ----
  unsigned short* w1h = (unsigned short*)d_ws;        // 128*256
  unsigned short* w1l = w1h + 128 * 256;
  unsigned short* w2h = w1l + 128 * 256;              // 256*256
  unsigned short* w2l = w2h + 256 * 256;
  unsigned short* w3h = w2l + 256 * 256;              // 256*256
  unsigned short* w3l = w3h + 256 * 256;
  unsigned short* w4h = w3l + 256 * 256;              // 256*128
  unsigned short* w4l = w4h + 256 * 128;
  unsigned short* PAh = w4l + 256 * 128;              // MR*256 bf16 (agg pairs)
  unsigned short* PAl = PAh + (size_t)MR * 256;
  unsigned short* PHh = PAl + (size_t)MR * 256;       // MR*256 bf16 (hidden pairs)
  unsigned short* PHl = PHh + (size_t)MR * 256;
  float* HF = (float*)(PHl + (size_t)MR * 256);       // MR*256 f32 (h1)
  int* off    = (int*)(HF + (size_t)MR * 256);        // M+1
  int* cursor = off + (M + 1);                        // M
  int* csr    = cursor + M;                           // E
  int* blksum = csr + E;                              // ~196

  dim3 blk(256);
  const int NB = (M + 255) / 256;

  // ---- weight prep ----
  prep_w<<<dim3(128 / 32, 256 / 64), blk, 0, stream>>>(W1, w1h, w1l, 128, 256);
  prep_w<<<dim3(256 / 32, 256 / 64), blk, 0, stream>>>(W2, w2h, w2l, 256, 256);
  prep_w<<<dim3(256 / 32, 256 / 64), blk, 0, stream>>>(W3, w3h, w3l, 256, 256);
  prep_w<<<dim3(256 / 32, 128 / 64), blk, 0, stream>>>(W4, w4h, w4l, 256, 128);

  // ---- CSR build ----
  zero_int_kernel<<<NB, blk, 0, stream>>>(cursor, M);
  hist_kernel<<<(E + 255) / 256, blk, 0, stream>>>(dst, cursor, E);
  blocksum_kernel<<<NB, blk, 0, stream>>>(cursor, blksum, M);
  scanblk_kernel<<<1, 1024, 0, stream>>>(blksum, off, NB, M);
  scatteroff_kernel<<<NB, blk, 0, stream>>>(blksum, off, cursor, M);
  fill_kernel<<<(E + 255) / 256, blk, 0, stream>>>(src, dst, cursor, csr, E);

  const int MB = (M + 127) / 128;  // 391

  // ---- layer 1 ----
  gather_agg_split<32><<<(M + 7) / 8, blk, 0, stream>>>(x, off, csr, PAh, PAl, M);
  gemm_bf16<0><<<dim3(MB, 2), blk, 0, stream>>>(PAh, PAl, w1h, w1l, b1, PHh, PHl, nullptr,
                                                M, 256, 128, nullptr, nullptr, nullptr);
  gemm_bf16<1><<<dim3(MB, 2), blk, 0, stream>>>(PHh, PHl, w2h, w2l, b2, nullptr, nullptr, HF,
                                                M, 256, 256, nullptr, nullptr, nullptr);
  // ---- layer 2 ----
  gather_agg_split<64><<<(M + 3) / 4, blk, 0, stream>>>(HF, off, csr, PAh, PAl, M);
  gemm_bf16<0><<<dim3(MB, 2), blk, 0, stream>>>(PAh, PAl, w3h, w3l, b3, PHh, PHl, nullptr,
                                                M, 256, 256, nullptr, nullptr, nullptr);
  gemm_bf16<2><<<dim3(MB, 1), blk, 0, stream>>>(PHh, PHl, w4h, w4l, b4, nullptr, nullptr, nullptr,
                                                M, 128, 256, W5, b5, out);
}

// Round 6
// 377.479 us; speedup vs baseline: 1.2097x; 1.2097x over previous
//
#include <hip/hip_runtime.h>
#include <hip/hip_fp16.h>

#define ALPHA 0.2f

typedef __attribute__((ext_vector_type(8))) short bf16x8;
typedef __attribute__((ext_vector_type(4))) float f32x4;

static __device__ __forceinline__ float leaky_f(float v) {
  return v >= 0.0f ? v : ALPHA * v;
}

static __device__ __forceinline__ unsigned short f2bf(float f) {
  unsigned u = __float_as_uint(f);
  unsigned r = (u + 0x7FFFu + ((u >> 16) & 1u)) >> 16;
  return (unsigned short)r;
}
static __device__ __forceinline__ float bf2f(unsigned short h) {
  return __uint_as_float(((unsigned)h) << 16);
}

typedef const __attribute__((address_space(1))) unsigned char* gas1_t;
typedef __attribute__((address_space(3))) unsigned char* las3_t;
static __device__ __forceinline__ void gll16(const void* g, void* l) {
  __builtin_amdgcn_global_load_lds((gas1_t)g, (las3_t)l, 16, 0, 0);
}

// unpack 8 fp16 (uint4) -> 8 f32 accumulate
static __device__ __forceinline__ void acc8(uint4 v, float* a) {
  const __half2* h = reinterpret_cast<const __half2*>(&v);
  #pragma unroll
  for (int i = 0; i < 4; ++i) {
    float2 t = __half22float2(h[i]);
    a[2 * i] += t.x;
    a[2 * i + 1] += t.y;
  }
}
static __device__ __forceinline__ void set8(uint4 v, float* a) {
  const __half2* h = reinterpret_cast<const __half2*>(&v);
  #pragma unroll
  for (int i = 0; i < 4; ++i) {
    float2 t = __half22float2(h[i]);
    a[2 * i] = t.x;
    a[2 * i + 1] = t.y;
  }
}

// ---------- CSR build ----------

__global__ __launch_bounds__(256) void zero_int_kernel(int* __restrict__ p, int n) {
  int i = blockIdx.x * blockDim.x + threadIdx.x;
  if (i < n) p[i] = 0;
}

__global__ __launch_bounds__(256) void hist_kernel(const int* __restrict__ dst,
                                                   int* __restrict__ cnt, int E) {
  int e = blockIdx.x * blockDim.x + threadIdx.x;
  if (e < E) atomicAdd(&cnt[dst[e]], 1);
}

__global__ __launch_bounds__(256) void blocksum_kernel(const int* __restrict__ deg,
                                                       int* __restrict__ blksum, int n) {
  __shared__ int red[4];
  int i = blockIdx.x * 256 + threadIdx.x;
  int v = (i < n) ? deg[i] : 0;
  #pragma unroll
  for (int off = 32; off; off >>= 1) v += __shfl_down(v, off, 64);
  int wv = threadIdx.x >> 6, ln = threadIdx.x & 63;
  if (ln == 0) red[wv] = v;
  __syncthreads();
  if (threadIdx.x == 0) blksum[blockIdx.x] = red[0] + red[1] + red[2] + red[3];
}

__global__ __launch_bounds__(1024) void scanblk_kernel(int* __restrict__ blksum,
                                                       int* __restrict__ off, int nb, int n) {
  __shared__ int s[1024];
  int t = threadIdx.x;
  int v = (t < nb) ? blksum[t] : 0;
  s[t] = v;
  __syncthreads();
  for (int d = 1; d < 1024; d <<= 1) {
    int u = (t >= d) ? s[t - d] : 0;
    __syncthreads();
    s[t] += u;
    __syncthreads();
  }
  if (t < nb) blksum[t] = s[t] - v;
  if (t == 0) off[n] = s[1023];
}

__global__ __launch_bounds__(256) void scatteroff_kernel(const int* __restrict__ blkoff,
                                                         int* __restrict__ off,
                                                         int* __restrict__ cursor, int n) {
  __shared__ int s[256];
  int i = blockIdx.x * 256 + threadIdx.x;
  int v = (i < n) ? cursor[i] : 0;
  s[threadIdx.x] = v;
  __syncthreads();
  for (int d = 1; d < 256; d <<= 1) {
    int u = (threadIdx.x >= d) ? s[threadIdx.x - d] : 0;
    __syncthreads();
    s[threadIdx.x] += u;
    __syncthreads();
  }
  int excl = s[threadIdx.x] - v + blkoff[blockIdx.x];
  if (i < n) {
    off[i] = excl;
    cursor[i] = excl;
  }
}

__global__ __launch_bounds__(256) void fill_kernel(const int* __restrict__ src,
                                                   const int* __restrict__ dst,
                                                   int* __restrict__ cursor,
                                                   int* __restrict__ csr, int E) {
  int e = blockIdx.x * blockDim.x + threadIdx.x;
  if (e < E) {
    int p = atomicAdd(&cursor[dst[e]], 1);
    csr[p] = src[e];
  }
}

// ---------- x f32 -> fp16 ----------
__global__ __launch_bounds__(256) void f32_to_f16_kernel(const float* __restrict__ in,
                                                         unsigned short* __restrict__ out, int n8) {
  int i = blockIdx.x * 256 + threadIdx.x;
  if (i >= n8) return;
  const float4* p = reinterpret_cast<const float4*>(in) + (size_t)i * 2;
  float4 v0 = p[0], v1 = p[1];
  float f[8] = {v0.x, v0.y, v0.z, v0.w, v1.x, v1.y, v1.z, v1.w};
  unsigned w[4];
  #pragma unroll
  for (int q = 0; q < 4; ++q) {
    unsigned short h0 = __half_as_ushort(__float2half_rn(f[2 * q]));
    unsigned short h1 = __half_as_ushort(__float2half_rn(f[2 * q + 1]));
    w[q] = (unsigned)h0 | ((unsigned)h1 << 16);
  }
  uint4 o; o.x = w[0]; o.y = w[1]; o.z = w[2]; o.w = w[3];
  reinterpret_cast<uint4*>(out)[i] = o;
}

// ---------- aggregation from fp16 rows: agg[i] = x[i] + sum_p x[csr[p]]; emits bf16 hi/lo ----------
// F8 = threads per node; each thread owns 8 contiguous fp16 (16B).
template <int F8>
__global__ __launch_bounds__(256) void gather_fp16(const unsigned short* __restrict__ xh,
                                                   const int* __restrict__ off,
                                                   const int* __restrict__ csr,
                                                   unsigned short* __restrict__ Ah,
                                                   unsigned short* __restrict__ Al,
                                                   int M) {
  constexpr int GP = 256 / F8;
  int g = threadIdx.x / F8;
  int lane = threadIdx.x % F8;
  int node = blockIdx.x * GP + g;
  if (node >= M) return;
  const uint4* xv = reinterpret_cast<const uint4*>(xh);
  float a0[8], a1[8], a2[8], a3[8];
  set8(xv[(size_t)node * F8 + lane], a0);
  #pragma unroll
  for (int i = 0; i < 8; ++i) { a1[i] = 0.f; a2[i] = 0.f; a3[i] = 0.f; }
  int p = off[node], p1 = off[node + 1];
  for (; p + 4 <= p1; p += 4) {
    int s0 = csr[p], s1 = csr[p + 1], s2 = csr[p + 2], s3 = csr[p + 3];
    uint4 v0 = xv[(size_t)s0 * F8 + lane];
    uint4 v1 = xv[(size_t)s1 * F8 + lane];
    uint4 v2 = xv[(size_t)s2 * F8 + lane];
    uint4 v3 = xv[(size_t)s3 * F8 + lane];
    acc8(v0, a0); acc8(v1, a1); acc8(v2, a2); acc8(v3, a3);
  }
  for (; p < p1; ++p) {
    uint4 v = xv[(size_t)csr[p] * F8 + lane];
    acc8(v, a0);
  }
  float r[8];
  #pragma unroll
  for (int i = 0; i < 8; ++i) r[i] = (a0[i] + a1[i]) + (a2[i] + a3[i]);
  unsigned hw[4], lw[4];
  #pragma unroll
  for (int q = 0; q < 4; ++q) {
    unsigned short h0 = f2bf(r[2 * q]);
    unsigned short h1 = f2bf(r[2 * q + 1]);
    unsigned short l0 = f2bf(r[2 * q] - bf2f(h0));
    unsigned short l1 = f2bf(r[2 * q + 1] - bf2f(h1));
    hw[q] = (unsigned)h0 | ((unsigned)h1 << 16);
    lw[q] = (unsigned)l0 | ((unsigned)l1 << 16);
  }
  uint4 hv, lv;
  hv.x = hw[0]; hv.y = hw[1]; hv.z = hw[2]; hv.w = hw[3];
  lv.x = lw[0]; lv.y = lw[1]; lv.z = lw[2]; lv.w = lw[3];
  size_t base = (size_t)node * F8 + lane;   // in uint4 units
  reinterpret_cast<uint4*>(Ah)[base] = hv;
  reinterpret_cast<uint4*>(Al)[base] = lv;
}

// ---------- weight prep: W [K][N] f32 -> Wh, Wl [N][K] bf16 ----------
__global__ __launch_bounds__(256) void prep_w(const float* __restrict__ W,
                                              unsigned short* __restrict__ Wh,
                                              unsigned short* __restrict__ Wl,
                                              int K, int N) {
  __shared__ float T[32][65];
  int k0 = blockIdx.x * 32, n0 = blockIdx.y * 64;
  int t = threadIdx.x;
  int nn = t & 63, kk0 = t >> 6;
  #pragma unroll
  for (int i = 0; i < 8; ++i) {
    int kk = kk0 + i * 4;
    T[kk][nn] = W[(size_t)(k0 + kk) * N + n0 + nn];
  }
  __syncthreads();
  int kk = t & 31, nb = t >> 5;
  #pragma unroll
  for (int i = 0; i < 8; ++i) {
    int n2 = nb + i * 8;
    float f = T[kk][n2];
    unsigned short h = f2bf(f);
    float r = f - bf2f(h);
    Wh[(size_t)(n0 + n2) * K + k0 + kk] = h;
    Wl[(size_t)(n0 + n2) * K + k0 + kk] = f2bf(r);
  }
}

// ---------- GEMM: C = leaky(A@W + bias), A pre-split bf16 hi/lo [M][K], W [N][K] hi/lo.
// OUT_MODE 0: write bf16 hi/lo pair; 1: write fp16; 2: fused out[row]=sum leaky*w5 + b5 (N==128)
template <int OUT_MODE>
__global__ __launch_bounds__(256, 3) void gemm_bf16(const unsigned short* __restrict__ Ah,
                                                    const unsigned short* __restrict__ Al,
                                                    const unsigned short* __restrict__ Bh,
                                                    const unsigned short* __restrict__ Bl,
                                                    const float* __restrict__ bias,
                                                    unsigned short* __restrict__ Ch,
                                                    unsigned short* __restrict__ Cl,
                                                    unsigned short* __restrict__ Ch16,
                                                    int M, int N, int K,
                                                    const float* __restrict__ w5,
                                                    const float* __restrict__ b5p,
                                                    float* __restrict__ out) {
  __shared__ unsigned short Ah_s[128 * 32];
  __shared__ unsigned short Al_s[128 * 32];
  __shared__ unsigned short Bh_s[128 * 32];
  __shared__ unsigned short Bl_s[128 * 32];
  __shared__ float part_s[128][2];

  const int tid = threadIdx.x;
  const int bm = blockIdx.x * 128, bn = blockIdx.y * 128;
  const int lane = tid & 63;
  const int wave = tid >> 6;
  const int wr = (wave >> 1) * 64;
  const int wc = (wave & 1) * 64;
  const int lrow = lane & 15;
  const int lslot = lane >> 4;

  f32x4 acc[4][4];
  #pragma unroll
  for (int mi = 0; mi < 4; ++mi)
    #pragma unroll
    for (int ni = 0; ni < 4; ++ni)
      acc[mi][ni] = (f32x4){0.f, 0.f, 0.f, 0.f};

  for (int k0 = 0; k0 < K; k0 += 32) {
    #pragma unroll
    for (int h = 0; h < 2; ++h) {
      int p = tid + h * 256;
      int row = p >> 2, seg = p & 3;
      size_t ga = (size_t)(bm + row) * K + k0 + seg * 8;
      size_t gb = (size_t)(bn + row) * K + k0 + seg * 8;
      int lo = p * 8;
      gll16(Ah + ga, Ah_s + lo);
      gll16(Al + ga, Al_s + lo);
      gll16(Bh + gb, Bh_s + lo);
      gll16(Bl + gb, Bl_s + lo);
    }
    __syncthreads();

    bf16x8 fah[4], fal[4], fbh[4], fbl[4];
    #pragma unroll
    for (int mi = 0; mi < 4; ++mi) {
      int off = (wr + mi * 16 + lrow) * 32 + lslot * 8;
      fah[mi] = *reinterpret_cast<const bf16x8*>(&Ah_s[off]);
      fal[mi] = *reinterpret_cast<const bf16x8*>(&Al_s[off]);
    }
    #pragma unroll
    for (int ni = 0; ni < 4; ++ni) {
      int off = (wc + ni * 16 + lrow) * 32 + lslot * 8;
      fbh[ni] = *reinterpret_cast<const bf16x8*>(&Bh_s[off]);
      fbl[ni] = *reinterpret_cast<const bf16x8*>(&Bl_s[off]);
    }
    #pragma unroll
    for (int mi = 0; mi < 4; ++mi)
      #pragma unroll
      for (int ni = 0; ni < 4; ++ni) {
        acc[mi][ni] = __builtin_amdgcn_mfma_f32_16x16x32_bf16(fah[mi], fbh[ni], acc[mi][ni], 0, 0, 0);
        acc[mi][ni] = __builtin_amdgcn_mfma_f32_16x16x32_bf16(fah[mi], fbl[ni], acc[mi][ni], 0, 0, 0);
        acc[mi][ni] = __builtin_amdgcn_mfma_f32_16x16x32_bf16(fal[mi], fbh[ni], acc[mi][ni], 0, 0, 0);
      }
    __syncthreads();
  }

  if (OUT_MODE == 2) {
    float w5v[4], bv[4];
    #pragma unroll
    for (int ni = 0; ni < 4; ++ni) {
      int col = wc + ni * 16 + lrow;
      w5v[ni] = w5[col];
      bv[ni] = bias[col];
    }
    #pragma unroll
    for (int mi = 0; mi < 4; ++mi) {
      #pragma unroll
      for (int j = 0; j < 4; ++j) {
        float s = 0.f;
        #pragma unroll
        for (int ni = 0; ni < 4; ++ni)
          s += leaky_f(acc[mi][ni][j] + bv[ni]) * w5v[ni];
        s += __shfl_xor(s, 1, 64);
        s += __shfl_xor(s, 2, 64);
        s += __shfl_xor(s, 4, 64);
        s += __shfl_xor(s, 8, 64);
        if (lrow == 0) part_s[wr + mi * 16 + lslot * 4 + j][wave & 1] = s;
      }
    }
    __syncthreads();
    if (tid < 128) {
      int row = bm + tid;
      if (row < M) out[row] = part_s[tid][0] + part_s[tid][1] + b5p[0];
    }
  } else {
    #pragma unroll
    for (int ni = 0; ni < 4; ++ni) {
      int col = bn + wc + ni * 16 + lrow;
      float bv = bias[col];
      #pragma unroll
      for (int mi = 0; mi < 4; ++mi) {
        int rbase = bm + wr + mi * 16 + lslot * 4;
        #pragma unroll
        for (int j = 0; j < 4; ++j) {
          int row = rbase + j;
          if (row < M) {
            float v = leaky_f(acc[mi][ni][j] + bv);
            if (OUT_MODE == 0) {
              unsigned short h = f2bf(v);
              Ch[(size_t)row * N + col] = h;
              Cl[(size_t)row * N + col] = f2bf(v - bf2f(h));
            } else {
              Ch16[(size_t)row * N + col] = __half_as_ushort(__float2half_rn(v));
            }
          }
        }
      }
    }
  }
}

extern "C" void kernel_launch(void* const* d_in, const int* in_sizes, int n_in,
                              void* d_out, int out_size, void* d_ws, size_t ws_size,
                              hipStream_t stream) {
  const float* x  = (const float*)d_in[0];
  const int*   ei = (const int*)d_in[2];
  const float* W1 = (const float*)d_in[3];
  const float* b1 = (const float*)d_in[4];
  const float* W2 = (const float*)d_in[5];
  const float* b2 = (const float*)d_in[6];
  const float* W3 = (const float*)d_in[7];
  const float* b3 = (const float*)d_in[8];
  const float* W4 = (const float*)d_in[9];
  const float* b4 = (const float*)d_in[10];
  const float* W5 = (const float*)d_in[11];
  const float* b5 = (const float*)d_in[12];
  float* out = (float*)d_out;

  const int M = in_sizes[0] / 128;  // 50000
  const int E = in_sizes[2] / 2;    // 800000
  const int* src = ei;
  const int* dst = ei + E;
  const int MR = ((M + 127) / 128) * 128;  // 50048

  // ---- workspace layout (all 16B aligned) ----
  unsigned short* w1h = (unsigned short*)d_ws;        // 128*256
  unsigned short* w1l = w1h + 128 * 256;
  unsigned short* w2h = w1l + 128 * 256;              // 256*256
  unsigned short* w2l = w2h + 256 * 256;
  unsigned short* w3h = w2l + 256 * 256;              // 256*256
  unsigned short* w3l = w3h + 256 * 256;
  unsigned short* w4h = w3l + 256 * 256;              // 256*128
  unsigned short* w4l = w4h + 256 * 128;
  unsigned short* PAh = w4l + 256 * 128;              // MR*256 bf16
  unsigned short* PAl = PAh + (size_t)MR * 256;
  unsigned short* PHh = PAl + (size_t)MR * 256;       // MR*256 bf16
  unsigned short* PHl = PHh + (size_t)MR * 256;
  unsigned short* H2  = PHl + (size_t)MR * 256;       // MR*256 fp16 (h1)
  unsigned short* XH  = H2 + (size_t)MR * 256;        // M*128 fp16 (x)
  int* off    = (int*)(XH + (size_t)M * 128);         // M+1
  int* cursor = off + (M + 1);                        // M
  int* csr    = cursor + M;                           // E
  int* blksum = csr + E;                              // ~196

  dim3 blk(256);
  const int NB = (M + 255) / 256;

  // ---- prep: weights + x fp16 ----
  prep_w<<<dim3(128 / 32, 256 / 64), blk, 0, stream>>>(W1, w1h, w1l, 128, 256);
  prep_w<<<dim3(256 / 32, 256 / 64), blk, 0, stream>>>(W2, w2h, w2l, 256, 256);
  prep_w<<<dim3(256 / 32, 256 / 64), blk, 0, stream>>>(W3, w3h, w3l, 256, 256);
  prep_w<<<dim3(256 / 32, 128 / 64), blk, 0, stream>>>(W4, w4h, w4l, 256, 128);
  {
    int n8 = M * 128 / 8;
    f32_to_f16_kernel<<<(n8 + 255) / 256, blk, 0, stream>>>(x, XH, n8);
  }

  // ---- CSR build ----
  zero_int_kernel<<<NB, blk, 0, stream>>>(cursor, M);
  hist_kernel<<<(E + 255) / 256, blk, 0, stream>>>(dst, cursor, E);
  blocksum_kernel<<<NB, blk, 0, stream>>>(cursor, blksum, M);
  scanblk_kernel<<<1, 1024, 0, stream>>>(blksum, off, NB, M);
  scatteroff_kernel<<<NB, blk, 0, stream>>>(blksum, off, cursor, M);
  fill_kernel<<<(E + 255) / 256, blk, 0, stream>>>(src, dst, cursor, csr, E);

  const int MB = (M + 127) / 128;  // 391

  // ---- layer 1 ----
  gather_fp16<16><<<(M * 16 + 255) / 256, blk, 0, stream>>>(XH, off, csr, PAh, PAl, M);
  gemm_bf16<0><<<dim3(MB, 2), blk, 0, stream>>>(PAh, PAl, w1h, w1l, b1, PHh, PHl, nullptr,
                                                M, 256, 128, nullptr, nullptr, nullptr);
  gemm_bf16<1><<<dim3(MB, 2), blk, 0, stream>>>(PHh, PHl, w2h, w2l, b2, nullptr, nullptr, H2,
                                                M, 256, 256, nullptr, nullptr, nullptr);
  // ---- layer 2 ----
  gather_fp16<32><<<(M * 32 + 255) / 256, blk, 0, stream>>>(H2, off, csr, PAh, PAl, M);
  gemm_bf16<0><<<dim3(MB, 2), blk, 0, stream>>>(PAh, PAl, w3h, w3l, b3, PHh, PHl, nullptr,
                                                M, 256, 256, nullptr, nullptr, nullptr);
  gemm_bf16<2><<<dim3(MB, 1), blk, 0, stream>>>(PHh, PHl, w4h, w4l, b4, nullptr, nullptr, nullptr,
                                                M, 128, 256, W5, b5, out);
}

// Round 7
// 290.104 us; speedup vs baseline: 1.5740x; 1.3012x over previous
//
#include <hip/hip_runtime.h>
#include <hip/hip_fp16.h>

#define ALPHA 0.2f

typedef __attribute__((ext_vector_type(8))) _Float16 f16x8;
typedef __attribute__((ext_vector_type(4))) float f32x4;

static __device__ __forceinline__ float leaky_f(float v) {
  return v >= 0.0f ? v : ALPHA * v;
}

typedef const __attribute__((address_space(1))) unsigned char* gas1_t;
typedef __attribute__((address_space(3))) unsigned char* las3_t;
static __device__ __forceinline__ void gll16(const void* g, void* l) {
  __builtin_amdgcn_global_load_lds((gas1_t)g, (las3_t)l, 16, 0, 0);
}

// ---------- CSR build ----------

__global__ __launch_bounds__(256) void zero_int_kernel(int* __restrict__ p, int n) {
  int i = blockIdx.x * blockDim.x + threadIdx.x;
  if (i < n) p[i] = 0;
}

__global__ __launch_bounds__(256) void hist_kernel(const int* __restrict__ dst,
                                                   int* __restrict__ cnt, int E) {
  int e = blockIdx.x * blockDim.x + threadIdx.x;
  if (e < E) atomicAdd(&cnt[dst[e]], 1);
}

__global__ __launch_bounds__(256) void blocksum_kernel(const int* __restrict__ deg,
                                                       int* __restrict__ blksum, int n) {
  __shared__ int red[4];
  int i = blockIdx.x * 256 + threadIdx.x;
  int v = (i < n) ? deg[i] : 0;
  #pragma unroll
  for (int off = 32; off; off >>= 1) v += __shfl_down(v, off, 64);
  int wv = threadIdx.x >> 6, ln = threadIdx.x & 63;
  if (ln == 0) red[wv] = v;
  __syncthreads();
  if (threadIdx.x == 0) blksum[blockIdx.x] = red[0] + red[1] + red[2] + red[3];
}

__global__ __launch_bounds__(1024) void scanblk_kernel(int* __restrict__ blksum,
                                                       int* __restrict__ off, int nb, int n) {
  __shared__ int s[1024];
  int t = threadIdx.x;
  int v = (t < nb) ? blksum[t] : 0;
  s[t] = v;
  __syncthreads();
  for (int d = 1; d < 1024; d <<= 1) {
    int u = (t >= d) ? s[t - d] : 0;
    __syncthreads();
    s[t] += u;
    __syncthreads();
  }
  if (t < nb) blksum[t] = s[t] - v;
  if (t == 0) off[n] = s[1023];
}

__global__ __launch_bounds__(256) void scatteroff_kernel(const int* __restrict__ blkoff,
                                                         int* __restrict__ off,
                                                         int* __restrict__ cursor, int n) {
  __shared__ int s[256];
  int i = blockIdx.x * 256 + threadIdx.x;
  int v = (i < n) ? cursor[i] : 0;
  s[threadIdx.x] = v;
  __syncthreads();
  for (int d = 1; d < 256; d <<= 1) {
    int u = (threadIdx.x >= d) ? s[threadIdx.x - d] : 0;
    __syncthreads();
    s[threadIdx.x] += u;
    __syncthreads();
  }
  int excl = s[threadIdx.x] - v + blkoff[blockIdx.x];
  if (i < n) {
    off[i] = excl;
    cursor[i] = excl;
  }
}

__global__ __launch_bounds__(256) void fill_kernel(const int* __restrict__ src,
                                                   const int* __restrict__ dst,
                                                   int* __restrict__ cursor,
                                                   int* __restrict__ csr, int E) {
  int e = blockIdx.x * blockDim.x + threadIdx.x;
  if (e < E) {
    int p = atomicAdd(&cursor[dst[e]], 1);
    csr[p] = src[e];
  }
}

// ---------- x f32 -> fp16 ----------
__global__ __launch_bounds__(256) void f32_to_f16_kernel(const float* __restrict__ in,
                                                         _Float16* __restrict__ out, int n8) {
  int i = blockIdx.x * 256 + threadIdx.x;
  if (i >= n8) return;
  const float4* p = reinterpret_cast<const float4*>(in) + (size_t)i * 2;
  float4 v0 = p[0], v1 = p[1];
  float f[8] = {v0.x, v0.y, v0.z, v0.w, v1.x, v1.y, v1.z, v1.w};
  f16x8 o;
  #pragma unroll
  for (int q = 0; q < 8; ++q) o[q] = (_Float16)f[q];
  reinterpret_cast<f16x8*>(out)[i] = o;
}

// ---------- aggregation: agg[i] = x[i] + sum_p x[csr[p]]; fp16 in, fp16 out ----------
// F8 = threads per node (each owns 8 fp16 = 16B).
template <int F8>
__global__ __launch_bounds__(256) void gather_f16(const _Float16* __restrict__ xh,
                                                  const int* __restrict__ off,
                                                  const int* __restrict__ csr,
                                                  _Float16* __restrict__ agg, int M) {
  constexpr int GP = 256 / F8;
  int g = threadIdx.x / F8;
  int lane = threadIdx.x % F8;
  int node = blockIdx.x * GP + g;
  if (node >= M) return;
  const f16x8* xv = reinterpret_cast<const f16x8*>(xh);
  float a0[8], a1[8], a2[8], a3[8];
  {
    f16x8 v = xv[(size_t)node * F8 + lane];
    #pragma unroll
    for (int i = 0; i < 8; ++i) { a0[i] = (float)v[i]; a1[i] = 0.f; a2[i] = 0.f; a3[i] = 0.f; }
  }
  int p = off[node], p1 = off[node + 1];
  for (; p + 4 <= p1; p += 4) {
    int s0 = csr[p], s1 = csr[p + 1], s2 = csr[p + 2], s3 = csr[p + 3];
    f16x8 v0 = xv[(size_t)s0 * F8 + lane];
    f16x8 v1 = xv[(size_t)s1 * F8 + lane];
    f16x8 v2 = xv[(size_t)s2 * F8 + lane];
    f16x8 v3 = xv[(size_t)s3 * F8 + lane];
    #pragma unroll
    for (int i = 0; i < 8; ++i) {
      a0[i] += (float)v0[i]; a1[i] += (float)v1[i];
      a2[i] += (float)v2[i]; a3[i] += (float)v3[i];
    }
  }
  for (; p < p1; ++p) {
    f16x8 v = xv[(size_t)csr[p] * F8 + lane];
    #pragma unroll
    for (int i = 0; i < 8; ++i) a0[i] += (float)v[i];
  }
  f16x8 o;
  #pragma unroll
  for (int i = 0; i < 8; ++i) o[i] = (_Float16)((a0[i] + a1[i]) + (a2[i] + a3[i]));
  reinterpret_cast<f16x8*>(agg)[(size_t)node * F8 + lane] = o;
}

// ---------- weight prep: W [K][N] f32 -> Wh, Wl [N][K] fp16 (hi/lo split) ----------
__global__ __launch_bounds__(256) void prep_w(const float* __restrict__ W,
                                              _Float16* __restrict__ Wh,
                                              _Float16* __restrict__ Wl,
                                              int K, int N) {
  __shared__ float T[32][65];
  int k0 = blockIdx.x * 32, n0 = blockIdx.y * 64;
  int t = threadIdx.x;
  int nn = t & 63, kk0 = t >> 6;
  #pragma unroll
  for (int i = 0; i < 8; ++i) {
    int kk = kk0 + i * 4;
    T[kk][nn] = W[(size_t)(k0 + kk) * N + n0 + nn];
  }
  __syncthreads();
  int kk = t & 31, nb = t >> 5;
  #pragma unroll
  for (int i = 0; i < 8; ++i) {
    int n2 = nb + i * 8;
    float f = T[kk][n2];
    _Float16 h = (_Float16)f;
    float r = f - (float)h;
    Wh[(size_t)(n0 + n2) * K + k0 + kk] = h;
    Wl[(size_t)(n0 + n2) * K + k0 + kk] = (_Float16)r;
  }
}

// ---------- GEMM: C = leaky(A@W + bias); A [M][K] fp16; Wh/Wl [N][K] fp16.
// 2 MFMA products: A*Wh + A*Wl (A is exactly fp16; only W is split).
// OUT_MODE 0: write fp16 C plane (vectorized via LDS); 2: fused out[row]=sum leaky*w5+b5 (N==128)
template <int OUT_MODE>
__global__ __launch_bounds__(256, 3) void gemm_f16(const _Float16* __restrict__ A,
                                                   const _Float16* __restrict__ Bh,
                                                   const _Float16* __restrict__ Bl,
                                                   const float* __restrict__ bias,
                                                   _Float16* __restrict__ C,
                                                   int M, int N, int K,
                                                   const float* __restrict__ w5,
                                                   const float* __restrict__ b5p,
                                                   float* __restrict__ out) {
  // 3 staging planes of 128x32 fp16 (8KB each); epilogue cbuf overlays plane 0..2
  __shared__ __align__(16) unsigned char smem[24576];
  __shared__ float part_s[128][2];
  _Float16* A_s  = (_Float16*)smem;
  _Float16* Bh_s = (_Float16*)(smem + 8192);
  _Float16* Bl_s = (_Float16*)(smem + 16384);

  const int tid = threadIdx.x;
  const int bm = blockIdx.x * 128, bn = blockIdx.y * 128;
  const int lane = tid & 63;
  const int wave = tid >> 6;
  const int wr = (wave >> 1) * 64;
  const int wc = (wave & 1) * 64;
  const int lrow = lane & 15;
  const int lslot = lane >> 4;

  f32x4 acc[4][4];
  #pragma unroll
  for (int mi = 0; mi < 4; ++mi)
    #pragma unroll
    for (int ni = 0; ni < 4; ++ni)
      acc[mi][ni] = (f32x4){0.f, 0.f, 0.f, 0.f};

  for (int k0 = 0; k0 < K; k0 += 32) {
    // stage 3 planes; LDS linear, global source pre-swizzled (seg ^ ((row>>1)&3))
    #pragma unroll
    for (int h = 0; h < 2; ++h) {
      int p = tid + h * 256;
      int row = p >> 2, s = p & 3;
      int sg = s ^ ((row >> 1) & 3);
      size_t ga = (size_t)(bm + row) * K + k0 + sg * 8;
      size_t gb = (size_t)(bn + row) * K + k0 + sg * 8;
      gll16(A + ga, smem + p * 16);
      gll16(Bh + gb, smem + 8192 + p * 16);
      gll16(Bl + gb, smem + 16384 + p * 16);
    }
    __syncthreads();

    f16x8 fa[4], fbh[4], fbl[4];
    #pragma unroll
    for (int mi = 0; mi < 4; ++mi) {
      int r = wr + mi * 16 + lrow;
      int off = r * 32 + ((lslot ^ ((r >> 1) & 3)) << 3);
      fa[mi] = *reinterpret_cast<const f16x8*>(&A_s[off]);
    }
    #pragma unroll
    for (int ni = 0; ni < 4; ++ni) {
      int r = wc + ni * 16 + lrow;
      int off = r * 32 + ((lslot ^ ((r >> 1) & 3)) << 3);
      fbh[ni] = *reinterpret_cast<const f16x8*>(&Bh_s[off]);
      fbl[ni] = *reinterpret_cast<const f16x8*>(&Bl_s[off]);
    }
    #pragma unroll
    for (int mi = 0; mi < 4; ++mi)
      #pragma unroll
      for (int ni = 0; ni < 4; ++ni) {
        acc[mi][ni] = __builtin_amdgcn_mfma_f32_16x16x32_f16(fa[mi], fbh[ni], acc[mi][ni], 0, 0, 0);
        acc[mi][ni] = __builtin_amdgcn_mfma_f32_16x16x32_f16(fa[mi], fbl[ni], acc[mi][ni], 0, 0, 0);
      }
    __syncthreads();
  }

  if (OUT_MODE == 2) {
    float w5v[4], bv[4];
    #pragma unroll
    for (int ni = 0; ni < 4; ++ni) {
      int col = wc + ni * 16 + lrow;
      w5v[ni] = w5[col];
      bv[ni] = bias[col];
    }
    #pragma unroll
    for (int mi = 0; mi < 4; ++mi) {
      #pragma unroll
      for (int j = 0; j < 4; ++j) {
        float s = 0.f;
        #pragma unroll
        for (int ni = 0; ni < 4; ++ni)
          s += leaky_f(acc[mi][ni][j] + bv[ni]) * w5v[ni];
        s += __shfl_xor(s, 1, 64);
        s += __shfl_xor(s, 2, 64);
        s += __shfl_xor(s, 4, 64);
        s += __shfl_xor(s, 8, 64);
        if (lrow == 0) part_s[wr + mi * 16 + lslot * 4 + j][wave & 1] = s;
      }
    }
    __syncthreads();
    if (tid < 128) {
      int row = bm + tid;
      if (row < M) out[row] = part_s[tid][0] + part_s[tid][1] + b5p[0];
    }
  } else {
    // vectorized epilogue: acc -> LDS fp16 [64][136] -> coalesced uint4 stores
    _Float16 (*cbuf)[136] = reinterpret_cast<_Float16 (*)[136]>(smem);
    float bv[4];
    #pragma unroll
    for (int ni = 0; ni < 4; ++ni) bv[ni] = bias[bn + wc + ni * 16 + lrow];
    #pragma unroll
    for (int half = 0; half < 2; ++half) {
      if (wr == half * 64) {
        #pragma unroll
        for (int mi = 0; mi < 4; ++mi)
          #pragma unroll
          for (int ni = 0; ni < 4; ++ni)
            #pragma unroll
            for (int j = 0; j < 4; ++j)
              cbuf[mi * 16 + lslot * 4 + j][wc + ni * 16 + lrow] =
                  (_Float16)leaky_f(acc[mi][ni][j] + bv[ni]);
      }
      __syncthreads();
      {
        int row = tid >> 2, cb = (tid & 3) * 32;
        int grow = bm + half * 64 + row;
        if (grow < M) {
          uint4* dst = reinterpret_cast<uint4*>(C + (size_t)grow * N + bn + cb);
          const uint4* srcp = reinterpret_cast<const uint4*>(&cbuf[row][cb]);
          dst[0] = srcp[0]; dst[1] = srcp[1]; dst[2] = srcp[2]; dst[3] = srcp[3];
        }
      }
      __syncthreads();
    }
  }
}

extern "C" void kernel_launch(void* const* d_in, const int* in_sizes, int n_in,
                              void* d_out, int out_size, void* d_ws, size_t ws_size,
                              hipStream_t stream) {
  const float* x  = (const float*)d_in[0];
  const int*   ei = (const int*)d_in[2];
  const float* W1 = (const float*)d_in[3];
  const float* b1 = (const float*)d_in[4];
  const float* W2 = (const float*)d_in[5];
  const float* b2 = (const float*)d_in[6];
  const float* W3 = (const float*)d_in[7];
  const float* b3 = (const float*)d_in[8];
  const float* W4 = (const float*)d_in[9];
  const float* b4 = (const float*)d_in[10];
  const float* W5 = (const float*)d_in[11];
  const float* b5 = (const float*)d_in[12];
  float* out = (float*)d_out;

  const int M = in_sizes[0] / 128;  // 50000
  const int E = in_sizes[2] / 2;    // 800000
  const int* src = ei;
  const int* dst = ei + E;
  const int MR = ((M + 127) / 128) * 128;  // 50048

  // ---- workspace layout (16B aligned) ----
  _Float16* w1h = (_Float16*)d_ws;                    // 256*128
  _Float16* w1l = w1h + 256 * 128;
  _Float16* w2h = w1l + 256 * 128;                    // 256*256
  _Float16* w2l = w2h + 256 * 256;
  _Float16* w3h = w2l + 256 * 256;                    // 256*256
  _Float16* w3l = w3h + 256 * 256;
  _Float16* w4h = w3l + 256 * 256;                    // 128*256
  _Float16* w4l = w4h + 128 * 256;
  _Float16* XH  = w4l + 128 * 256;                    // M*128 fp16 (x)
  _Float16* AG1 = XH + (size_t)M * 128;               // MR*128 (agg1)
  _Float16* T   = AG1 + (size_t)MR * 128;             // MR*256 (t1 / t2)
  _Float16* H2  = T + (size_t)MR * 256;               // MR*256 (h1)
  _Float16* AG2 = H2 + (size_t)MR * 256;              // MR*256 (agg2)
  int* off    = (int*)(AG2 + (size_t)MR * 256);       // M+1
  int* cursor = off + (M + 1);                        // M
  int* csr    = cursor + M;                           // E
  int* blksum = csr + E;                              // ~196

  dim3 blk(256);
  const int NB = (M + 255) / 256;

  // ---- prep: weights + x fp16 ----
  prep_w<<<dim3(128 / 32, 256 / 64), blk, 0, stream>>>(W1, w1h, w1l, 128, 256);
  prep_w<<<dim3(256 / 32, 256 / 64), blk, 0, stream>>>(W2, w2h, w2l, 256, 256);
  prep_w<<<dim3(256 / 32, 256 / 64), blk, 0, stream>>>(W3, w3h, w3l, 256, 256);
  prep_w<<<dim3(256 / 32, 128 / 64), blk, 0, stream>>>(W4, w4h, w4l, 256, 128);
  {
    int n8 = M * 128 / 8;
    f32_to_f16_kernel<<<(n8 + 255) / 256, blk, 0, stream>>>(x, XH, n8);
  }

  // ---- CSR build ----
  zero_int_kernel<<<NB, blk, 0, stream>>>(cursor, M);
  hist_kernel<<<(E + 255) / 256, blk, 0, stream>>>(dst, cursor, E);
  blocksum_kernel<<<NB, blk, 0, stream>>>(cursor, blksum, M);
  scanblk_kernel<<<1, 1024, 0, stream>>>(blksum, off, NB, M);
  scatteroff_kernel<<<NB, blk, 0, stream>>>(blksum, off, cursor, M);
  fill_kernel<<<(E + 255) / 256, blk, 0, stream>>>(src, dst, cursor, csr, E);

  const int MB = (M + 127) / 128;  // 391

  // ---- layer 1 ----
  gather_f16<16><<<(M * 16 + 255) / 256, blk, 0, stream>>>(XH, off, csr, AG1, M);
  gemm_f16<0><<<dim3(MB, 2), blk, 0, stream>>>(AG1, w1h, w1l, b1, T, M, 256, 128,
                                               nullptr, nullptr, nullptr);
  gemm_f16<0><<<dim3(MB, 2), blk, 0, stream>>>(T, w2h, w2l, b2, H2, M, 256, 256,
                                               nullptr, nullptr, nullptr);
  // ---- layer 2 ----
  gather_f16<32><<<(M * 32 + 255) / 256, blk, 0, stream>>>(H2, off, csr, AG2, M);
  gemm_f16<0><<<dim3(MB, 2), blk, 0, stream>>>(AG2, w3h, w3l, b3, T, M, 256, 256,
                                               nullptr, nullptr, nullptr);
  gemm_f16<2><<<dim3(MB, 1), blk, 0, stream>>>(T, w4h, w4l, b4, nullptr, M, 128, 256,
                                               W5, b5, out);
}